// Round 4
// baseline (506.220 us; speedup 1.0000x reference)
//
#include <hip/hip_runtime.h>
#include <math.h>

// Problem dims (fixed by reference)
#define T_DIM 512
#define H_DIM 2048
#define I_DIM 1024
#define E_DIM 16
#define NP    2048          // T*K pairs
#define PM    256           // pairs per chunk: >= max expert count -> 1 chunk/expert, weights read ONCE
#define MAXCH 24            // worst-case chunks: NP/PM + E_DIM
#define LIST_OFF 256        // int offset of sorted pair list in ws
#define XB_OFF   8192       // float offset of bf16 x copy (512*2048 bf16 = 2 MB = 524288 floats)
#define HWS_OFF  (XB_OFF + 524288)  // float offset of h buffer in ws
#define BK    128           // K staged per iteration == scale block size
#define LDK   136           // padded bf16 leading dim (272 B row stride -> 2-way bank aliasing = free)

typedef float  float4v __attribute__((ext_vector_type(4)));
typedef short  short8v __attribute__((ext_vector_type(8)));

// f32 -> bf16 round-to-nearest-even (bit pattern) — scalar path (epilogue only)
__device__ __forceinline__ unsigned int bfr(float f) {
    unsigned int u = __builtin_bit_cast(unsigned int, f);
    return (u + 0x7fffu + ((u >> 16) & 1u)) >> 16;
}
// HW packed f32x2 -> bf16x2, RNE (gfx950 v_cvt_pk_bf16_f32). lo=a, hi=b.
__device__ __forceinline__ unsigned int cvt2(float a, float b) {
    unsigned int r;
    asm("v_cvt_pk_bf16_f32 %0, %1, %2" : "=v"(r) : "v"(a), "v"(b));
    return r;
}

// ---- x f32 -> bf16 prepass: 1M elements, read 4 MB write 2 MB ----
__global__ __launch_bounds__(256) void xprep_kernel(const float* __restrict__ x,
                                                    unsigned short* __restrict__ xb) {
    int idx = (blockIdx.x * 256 + threadIdx.x) * 16;   // grid 256 -> covers 1,048,576
    float4 a = *(const float4*)(x + idx);
    float4 b = *(const float4*)(x + idx + 4);
    float4 c = *(const float4*)(x + idx + 8);
    float4 d = *(const float4*)(x + idx + 12);
    uint4 lo = make_uint4(cvt2(a.x, a.y), cvt2(a.z, a.w), cvt2(b.x, b.y), cvt2(b.z, b.w));
    uint4 hi = make_uint4(cvt2(c.x, c.y), cvt2(c.z, c.w), cvt2(d.x, d.y), cvt2(d.z, d.w));
    *(uint4*)(xb + idx) = lo;
    *(uint4*)(xb + idx + 8) = hi;
}

// ---- fused routing: count -> plan -> scatter in ONE block ----
__global__ __launch_bounds__(1024) void route_kernel(const int* __restrict__ sel,
                                                     int* __restrict__ meta) {
    __shared__ int cnt[E_DIM];
    __shared__ int wptr[E_DIM];
    int tid = threadIdx.x;
    if (tid < E_DIM) cnt[tid] = 0;
    __syncthreads();
    int p0 = tid, p1 = tid + 1024;
    int e0 = sel[p0], e1 = sel[p1];
    atomicAdd(&cnt[e0], 1);
    atomicAdd(&cnt[e1], 1);
    for (int i = tid; i < MAXCH * PM; i += 1024) meta[LIST_OFF + i] = -1;
    __syncthreads();
    if (tid == 0) {
        int off = 0, ci = 0;
        for (int e = 0; e < E_DIM; ++e) {
            wptr[e] = off;
            int nch = (cnt[e] + PM - 1) / PM;
            for (int j = 0; j < nch; ++j) meta[32 + ci++] = e;
            off += nch * PM;
        }
        for (; ci < MAXCH; ++ci) meta[32 + ci] = -1;
    }
    __syncthreads();
    int pos0 = atomicAdd(&wptr[e0], 1);
    meta[LIST_OFF + pos0] = p0;
    int pos1 = atomicAdd(&wptr[e1], 1);
    meta[LIST_OFF + pos1] = p1;
}

// ---- GEMM 1 (MFMA bf16): h = silu(x.w0d^T) * (x.w1d^T), 256(pairs) x 64(i) tile ----
// 1024 threads = 16 waves; wave-tile 16(pairs) x 64(i). One chunk per expert ->
// weights read exactly once; x comes from the 2 MB bf16 copy (L2/L3-resident).
__global__ __launch_bounds__(1024, 4) void gemm01_kernel(
    const unsigned short* __restrict__ xb, const float* __restrict__ w0g,
    const float* __restrict__ w1g, const float* __restrict__ s0,
    const float* __restrict__ s1, const int* __restrict__ meta,
    unsigned short* __restrict__ hbuf) {
    int e = meta[32 + blockIdx.y];
    if (e < 0) return;
    int itile = blockIdx.x;                 // 0..15 (I/64)
    int tid = threadIdx.x;

    __shared__ unsigned short xs[PM][LDK];  // 69.6 KB
    __shared__ unsigned short as[64][LDK];  // 17.4 KB
    __shared__ unsigned short bs[64][LDK];  // 17.4 KB
    __shared__ int prow[PM];
    __shared__ int trow[PM];

    if (tid < PM) {
        int p = meta[LIST_OFF + blockIdx.y * PM + tid];
        prow[tid] = p;
        trow[tid] = p >= 0 ? (p >> 2) : 0;  // token = pair/4
    }
    __syncthreads();

    const int lane = tid & 63;
    const int wid  = tid >> 6;              // 0..15 -> 16-row m-strip
    const int l15  = lane & 15;
    const int kq   = (lane >> 4) * 8;       // fragment k sub-offset
    const int ib   = itile >> 1;            // i-block (128) for scales

    float4v zero = {0.f, 0.f, 0.f, 0.f};
    float4v accg[4], accu[4];
#pragma unroll
    for (int t = 0; t < 4; ++t) { accg[t] = zero; accu[t] = zero; }

    // staging maps: x = 4 thr/row x 32 bf16; weights = 16 thr/row x 8 f32
    const int rx = tid >> 2, cx = tid & 3;
    const int rw_ = tid >> 4, cw = tid & 15;
    const unsigned short* xrow = xb + (size_t)trow[rx] * H_DIM + cx * 32;
    const float* w0row = w0g + ((size_t)e * I_DIM + itile * 64 + rw_) * H_DIM + cw * 8;
    const float* w1row = w1g + ((size_t)e * I_DIM + itile * 64 + rw_) * H_DIM + cw * 8;
    const float* s0p = s0 + ((size_t)e * (I_DIM/128) + ib) * (H_DIM/128);
    const float* s1p = s1 + ((size_t)e * (I_DIM/128) + ib) * (H_DIM/128);

    uint4  px[4];
    float4 pa0, pa1, pb0, pb1;
#pragma unroll
    for (int q = 0; q < 4; ++q) px[q] = *(const uint4*)(xrow + q * 8);
    pa0 = *(const float4*)(w0row);
    pa1 = *(const float4*)(w0row + 4);
    pb0 = *(const float4*)(w1row);
    pb1 = *(const float4*)(w1row + 4);

    for (int hb = 0; hb < H_DIM / BK; ++hb) {     // 16 steps == 16 scale blocks
        float sg = s0p[hb];
        float su = s1p[hb];
#pragma unroll
        for (int j = 0; j < 4; ++j)               // x: already bf16, pure copy
            *(uint4*)&xs[rx][cx * 32 + j * 8] = px[j];
        *(uint4*)&as[rw_][cw * 8] = make_uint4(
            cvt2(pa0.x * sg, pa0.y * sg), cvt2(pa0.z * sg, pa0.w * sg),
            cvt2(pa1.x * sg, pa1.y * sg), cvt2(pa1.z * sg, pa1.w * sg));
        *(uint4*)&bs[rw_][cw * 8] = make_uint4(
            cvt2(pb0.x * su, pb0.y * su), cvt2(pb0.z * su, pb0.w * su),
            cvt2(pb1.x * su, pb1.y * su), cvt2(pb1.z * su, pb1.w * su));
        __syncthreads();
        if (hb + 1 < H_DIM / BK) {                // prefetch next step (hidden by MFMA)
            const int h0 = (hb + 1) * BK;
#pragma unroll
            for (int q = 0; q < 4; ++q) px[q] = *(const uint4*)(xrow + h0 + q * 8);
            pa0 = *(const float4*)(w0row + h0);
            pa1 = *(const float4*)(w0row + h0 + 4);
            pb0 = *(const float4*)(w1row + h0);
            pb1 = *(const float4*)(w1row + h0 + 4);
        }
#pragma unroll
        for (int ks = 0; ks < BK / 32; ++ks) {
            int koff = ks * 32 + kq;
            short8v af = *(const short8v*)&xs[wid * 16 + l15][koff];
#pragma unroll
            for (int nt = 0; nt < 4; ++nt) {
                short8v b0 = *(const short8v*)&as[nt * 16 + l15][koff];
                accg[nt] = __builtin_amdgcn_mfma_f32_16x16x32_bf16(af, b0, accg[nt], 0, 0, 0);
                short8v b1 = *(const short8v*)&bs[nt * 16 + l15][koff];
                accu[nt] = __builtin_amdgcn_mfma_f32_16x16x32_bf16(af, b1, accu[nt], 0, 0, 0);
            }
        }
        __syncthreads();
    }

    // epilogue: C layout col=lane&15 (i), row=(lane>>4)*4+reg (pair)
    int rowb = wid * 16 + (lane >> 4) * 4;
    int colb = itile * 64 + l15;
#pragma unroll
    for (int nt = 0; nt < 4; ++nt) {
#pragma unroll
        for (int rg = 0; rg < 4; ++rg) {
            int p = prow[rowb + rg];
            if (p < 0) continue;
            float g = accg[nt][rg], u = accu[nt][rg];
            float h = g / (1.f + __expf(-g)) * u;
            hbuf[(size_t)p * I_DIM + colb + nt * 16] = (unsigned short)bfr(h);
        }
    }
}

// ---- GEMM 2 (MFMA bf16): out[p,:] = (h.w2d^T) * rw[p], 256(pairs) x 128(h) tile ----
// 1024 threads = 16 waves; wave-tile 16 x 128 (nt=8). grid: x = htile (16), y = chunk.
// htile=128 halves hbuf re-reads vs 64-wide tiles; w2 still read exactly once.
__global__ __launch_bounds__(1024, 4) void gemm2_kernel(
    const unsigned short* __restrict__ hbuf, const float* __restrict__ w2g,
    const float* __restrict__ s2, const float* __restrict__ rw,
    const int* __restrict__ meta, float* __restrict__ out) {
    int e = meta[32 + blockIdx.y];
    if (e < 0) return;
    int htile = blockIdx.x;                 // 0..15 (H/128)
    int tid = threadIdx.x;

    __shared__ unsigned short hs[PM][LDK];  // 69.6 KB
    __shared__ unsigned short wsm[128][LDK];// 34.8 KB
    __shared__ int prow[PM];

    if (tid < PM) prow[tid] = meta[LIST_OFF + blockIdx.y * PM + tid];
    __syncthreads();

    const int lane = tid & 63;
    const int wid  = tid >> 6;              // 0..15
    const int l15  = lane & 15;
    const int kq   = (lane >> 4) * 8;

    float4v zero = {0.f, 0.f, 0.f, 0.f};
    float4v acc[8];
#pragma unroll
    for (int t = 0; t < 8; ++t) acc[t] = zero;

    const int rx = tid >> 2, cx = tid & 3;   // h: 4 thr/row x 32 bf16
    const int rw_ = tid >> 3, cw = tid & 7;  // w2: 8 thr/row x 16 f32
    int pr = prow[rx]; if (pr < 0) pr = 0;
    const unsigned short* hrow = hbuf + (size_t)pr * I_DIM + cx * 32;
    const float* wrow = w2g + ((size_t)e * H_DIM + htile * 128 + rw_) * I_DIM + cw * 16;
    const float* s2p = s2 + ((size_t)e * (H_DIM/128) + htile) * (I_DIM/128);

    uint4  ph[4];
    float4 pw[4];
#pragma unroll
    for (int q = 0; q < 4; ++q) {           // prologue: load step 0
        ph[q] = *(const uint4*)(hrow + q * 8);
        pw[q] = *(const float4*)(wrow + q * 4);
    }

    for (int ibk = 0; ibk < I_DIM / BK; ++ibk) {  // 8 steps == 8 scale blocks
        float sc = s2p[ibk];
#pragma unroll
        for (int q = 0; q < 4; ++q)
            *(uint4*)&hs[rx][cx * 32 + q * 8] = ph[q];   // already bf16
        *(uint4*)&wsm[rw_][cw * 16] = make_uint4(
            cvt2(pw[0].x * sc, pw[0].y * sc), cvt2(pw[0].z * sc, pw[0].w * sc),
            cvt2(pw[1].x * sc, pw[1].y * sc), cvt2(pw[1].z * sc, pw[1].w * sc));
        *(uint4*)&wsm[rw_][cw * 16 + 8] = make_uint4(
            cvt2(pw[2].x * sc, pw[2].y * sc), cvt2(pw[2].z * sc, pw[2].w * sc),
            cvt2(pw[3].x * sc, pw[3].y * sc), cvt2(pw[3].z * sc, pw[3].w * sc));
        __syncthreads();
        if (ibk + 1 < I_DIM / BK) {               // prefetch next step
            const int i0 = (ibk + 1) * BK;
#pragma unroll
            for (int q = 0; q < 4; ++q) {
                ph[q] = *(const uint4*)(hrow + i0 + q * 8);
                pw[q] = *(const float4*)(wrow + i0 + q * 4);
            }
        }
#pragma unroll
        for (int ks = 0; ks < BK / 32; ++ks) {
            int koff = ks * 32 + kq;
            short8v af = *(const short8v*)&hs[wid * 16 + l15][koff];
#pragma unroll
            for (int nt = 0; nt < 8; ++nt) {
                short8v bfv = *(const short8v*)&wsm[nt * 16 + l15][koff];
                acc[nt] = __builtin_amdgcn_mfma_f32_16x16x32_bf16(af, bfv, acc[nt], 0, 0, 0);
            }
        }
        __syncthreads();
    }

    int rowb = wid * 16 + (lane >> 4) * 4;
    int colb = htile * 128 + l15;
#pragma unroll
    for (int nt = 0; nt < 8; ++nt) {
#pragma unroll
        for (int rg = 0; rg < 4; ++rg) {
            int p = prow[rowb + rg];
            if (p < 0) continue;
            out[(size_t)p * H_DIM + colb + nt * 16] = acc[nt][rg] * rw[p];
        }
    }
}

extern "C" void kernel_launch(void* const* d_in, const int* in_sizes, int n_in,
                              void* d_out, int out_size, void* d_ws, size_t ws_size,
                              hipStream_t stream) {
    const float* x  = (const float*)d_in[0];
    const float* w0 = (const float*)d_in[1];
    const float* w1 = (const float*)d_in[2];
    const float* w2 = (const float*)d_in[3];
    const float* s0 = (const float*)d_in[4];
    const float* s1 = (const float*)d_in[5];
    const float* s2 = (const float*)d_in[6];
    const int* sel  = (const int*)d_in[7];
    const float* rw = (const float*)d_in[8];
    float* out = (float*)d_out;
    int* meta = (int*)d_ws;
    unsigned short* xb   = (unsigned short*)((float*)d_ws + XB_OFF);   // 2 MB bf16 x
    unsigned short* hbuf = (unsigned short*)((float*)d_ws + HWS_OFF);  // 4 MB bf16 h

    xprep_kernel<<<256, 256, 0, stream>>>(x, xb);
    route_kernel<<<1, 1024, 0, stream>>>(sel, meta);
    gemm01_kernel<<<dim3(I_DIM / 64, MAXCH), 1024, 0, stream>>>(xb, w0, w1, s0, s1, meta, hbuf);
    gemm2_kernel<<<dim3(H_DIM / 128, MAXCH), 1024, 0, stream>>>(hbuf, w2, s2, rw, meta, out);
}

// Round 5
// 420.512 us; speedup vs baseline: 1.2038x; 1.2038x over previous
//
#include <hip/hip_runtime.h>
#include <math.h>

// Problem dims (fixed by reference)
#define T_DIM 512
#define H_DIM 2048
#define I_DIM 1024
#define E_DIM 16
#define NP    2048          // T*K pairs
#define PM    256           // pairs per chunk: >= max expert count -> 1 chunk/expert, weights read ONCE
#define MAXCH 24            // worst-case chunks: NP/PM + E_DIM
#define LIST_OFF 256        // int offset of sorted pair list in ws
#define HWS_OFF  8192       // float offset of h buffer in ws (list needs 256+24*256=6400 ints)
#define BK2   64            // K staged per step (half a scale block)
#define LDB   72            // padded bf16 leading dim (144 B stride -> 2-way bank aliasing = free)

typedef float  float4v __attribute__((ext_vector_type(4)));
typedef short  short8v __attribute__((ext_vector_type(8)));

// f32 -> bf16 round-to-nearest-even (bit pattern) — epilogue only
__device__ __forceinline__ unsigned int bfr(float f) {
    unsigned int u = __builtin_bit_cast(unsigned int, f);
    return (u + 0x7fffu + ((u >> 16) & 1u)) >> 16;
}
// HW packed f32x2 -> bf16x2, RNE (gfx950 v_cvt_pk_bf16_f32). lo=a, hi=b.
__device__ __forceinline__ unsigned int cvt2(float a, float b) {
    unsigned int r;
    asm("v_cvt_pk_bf16_f32 %0, %1, %2" : "=v"(r) : "v"(a), "v"(b));
    return r;
}

// ---- fused routing: count -> plan -> scatter in ONE block ----
__global__ __launch_bounds__(1024) void route_kernel(const int* __restrict__ sel,
                                                     int* __restrict__ meta) {
    __shared__ int cnt[E_DIM];
    __shared__ int wptr[E_DIM];
    int tid = threadIdx.x;
    if (tid < E_DIM) cnt[tid] = 0;
    __syncthreads();
    int p0 = tid, p1 = tid + 1024;
    int e0 = sel[p0], e1 = sel[p1];
    atomicAdd(&cnt[e0], 1);
    atomicAdd(&cnt[e1], 1);
    for (int i = tid; i < MAXCH * PM; i += 1024) meta[LIST_OFF + i] = -1;
    __syncthreads();
    if (tid == 0) {
        int off = 0, ci = 0;
        for (int e = 0; e < E_DIM; ++e) {
            wptr[e] = off;
            int nch = (cnt[e] + PM - 1) / PM;
            for (int j = 0; j < nch; ++j) meta[32 + ci++] = e;
            off += nch * PM;
        }
        for (; ci < MAXCH; ++ci) meta[32 + ci] = -1;
    }
    __syncthreads();
    int pos0 = atomicAdd(&wptr[e0], 1);
    meta[LIST_OFF + pos0] = p0;
    int pos1 = atomicAdd(&wptr[e1], 1);
    meta[LIST_OFF + pos1] = p1;
}

// ---- GEMM 1 (MFMA bf16): h = silu(x.w0d^T) * (x.w1d^T), 256(pairs) x 64(i) tile ----
// 1024 threads = 16 waves; wave-tile 16(pairs) x 64(i). Weights read exactly once.
// Pipelined: per step, issue next-step loads FIRST (sched_barrier pins them above
// MFMA), compute on buf[cur], then cvt+write buf[cur^1]; ONE barrier per step.
__global__ __launch_bounds__(1024, 4) void gemm01_kernel(
    const float* __restrict__ x, const float* __restrict__ w0g,
    const float* __restrict__ w1g, const float* __restrict__ s0,
    const float* __restrict__ s1, const int* __restrict__ meta,
    unsigned short* __restrict__ hbuf) {
    int e = meta[32 + blockIdx.y];
    if (e < 0) return;
    int itile = blockIdx.x;                 // 0..15 (I/64)
    int tid = threadIdx.x;

    __shared__ unsigned short xs[2][PM][LDB];   // 72 KB
    __shared__ unsigned short as_[2][64][LDB];  // 18 KB
    __shared__ unsigned short bs_[2][64][LDB];  // 18 KB
    __shared__ int prow[PM];
    __shared__ int trow[PM];

    if (tid < PM) {
        int p = meta[LIST_OFF + blockIdx.y * PM + tid];
        prow[tid] = p;
        trow[tid] = p >= 0 ? (p >> 2) : 0;  // token = pair/4
    }
    __syncthreads();

    const int lane = tid & 63;
    const int wid  = tid >> 6;              // 0..15 -> 16-row m-strip
    const int l15  = lane & 15;
    const int kq   = (lane >> 4) * 8;       // fragment k sub-offset
    const int ib   = itile >> 1;            // i-block (128) for scales

    float4v zero = {0.f, 0.f, 0.f, 0.f};
    float4v accg[4], accu[4];
#pragma unroll
    for (int t = 0; t < 4; ++t) { accg[t] = zero; accu[t] = zero; }

    // staging maps: x = 4 thr/row x 16 f32; weights = 16 thr/row x 4 f32
    const int rx = tid >> 2, cx = tid & 3;
    const int rww = tid >> 4, cw = tid & 15;
    const float* xrow  = x   + (size_t)trow[rx] * H_DIM + cx * 16;
    const float* w0row = w0g + ((size_t)e * I_DIM + itile * 64 + rww) * H_DIM + cw * 4;
    const float* w1row = w1g + ((size_t)e * I_DIM + itile * 64 + rww) * H_DIM + cw * 4;
    const float* s0p = s0 + ((size_t)e * (I_DIM/128) + ib) * (H_DIM/128);
    const float* s1p = s1 + ((size_t)e * (I_DIM/128) + ib) * (H_DIM/128);

    float4 px[4], pa, pb;
#pragma unroll
    for (int q = 0; q < 4; ++q) px[q] = *(const float4*)(xrow + q * 4);
    pa = *(const float4*)(w0row);
    pb = *(const float4*)(w1row);
    {   // prologue: write step 0 into buf 0
        float sg = s0p[0], su = s1p[0];
#pragma unroll
        for (int j = 0; j < 2; ++j)
            *(uint4*)&xs[0][rx][cx * 16 + j * 8] = make_uint4(
                cvt2(px[2*j].x, px[2*j].y),   cvt2(px[2*j].z, px[2*j].w),
                cvt2(px[2*j+1].x, px[2*j+1].y), cvt2(px[2*j+1].z, px[2*j+1].w));
        *(uint2*)&as_[0][rww][cw * 4] = make_uint2(cvt2(pa.x * sg, pa.y * sg),
                                                   cvt2(pa.z * sg, pa.w * sg));
        *(uint2*)&bs_[0][rww][cw * 4] = make_uint2(cvt2(pb.x * su, pb.y * su),
                                                   cvt2(pb.z * su, pb.w * su));
    }
    __syncthreads();

    const int NT = H_DIM / BK2;             // 32 steps
    int cur = 0;
    for (int t = 0; t < NT; ++t) {
        if (t + 1 < NT) {                   // issue next-step loads FIRST
            const int h0 = (t + 1) * BK2;
#pragma unroll
            for (int q = 0; q < 4; ++q) px[q] = *(const float4*)(xrow + h0 + q * 4);
            pa = *(const float4*)(w0row + h0);
            pb = *(const float4*)(w1row + h0);
        }
        __builtin_amdgcn_sched_barrier(0);  // pin loads above the MFMA phase
#pragma unroll
        for (int ks = 0; ks < BK2 / 32; ++ks) {
            int koff = ks * 32 + kq;
            short8v af = *(const short8v*)&xs[cur][wid * 16 + l15][koff];
#pragma unroll
            for (int nt = 0; nt < 4; ++nt) {
                short8v b0 = *(const short8v*)&as_[cur][nt * 16 + l15][koff];
                accg[nt] = __builtin_amdgcn_mfma_f32_16x16x32_bf16(af, b0, accg[nt], 0, 0, 0);
                short8v b1 = *(const short8v*)&bs_[cur][nt * 16 + l15][koff];
                accu[nt] = __builtin_amdgcn_mfma_f32_16x16x32_bf16(af, b1, accu[nt], 0, 0, 0);
            }
        }
        if (t + 1 < NT) {                   // cvt + write buf[cur^1] (auto vmcnt here)
            float sg = s0p[(t + 1) >> 1], su = s1p[(t + 1) >> 1];
#pragma unroll
            for (int j = 0; j < 2; ++j)
                *(uint4*)&xs[cur ^ 1][rx][cx * 16 + j * 8] = make_uint4(
                    cvt2(px[2*j].x, px[2*j].y),   cvt2(px[2*j].z, px[2*j].w),
                    cvt2(px[2*j+1].x, px[2*j+1].y), cvt2(px[2*j+1].z, px[2*j+1].w));
            *(uint2*)&as_[cur ^ 1][rww][cw * 4] = make_uint2(cvt2(pa.x * sg, pa.y * sg),
                                                             cvt2(pa.z * sg, pa.w * sg));
            *(uint2*)&bs_[cur ^ 1][rww][cw * 4] = make_uint2(cvt2(pb.x * su, pb.y * su),
                                                             cvt2(pb.z * su, pb.w * su));
        }
        __syncthreads();
        cur ^= 1;
    }

    // epilogue: C layout col=lane&15 (i), row=(lane>>4)*4+reg (pair)
    int rowb = wid * 16 + (lane >> 4) * 4;
    int colb = itile * 64 + l15;
#pragma unroll
    for (int nt = 0; nt < 4; ++nt) {
#pragma unroll
        for (int rg = 0; rg < 4; ++rg) {
            int p = prow[rowb + rg];
            if (p < 0) continue;
            float g = accg[nt][rg], u = accu[nt][rg];
            float h = g / (1.f + __expf(-g)) * u;
            hbuf[(size_t)p * I_DIM + colb + nt * 16] = (unsigned short)bfr(h);
        }
    }
}

// ---- GEMM 2 (MFMA bf16): out[p,:] = (h.w2d^T) * rw[p], 256(pairs) x 64(h) tile ----
// Same pipelined structure. 1024 threads = 16 waves. grid: x = htile (32), y = chunk.
__global__ __launch_bounds__(1024, 4) void gemm2_kernel(
    const unsigned short* __restrict__ hbuf, const float* __restrict__ w2g,
    const float* __restrict__ s2, const float* __restrict__ rw,
    const int* __restrict__ meta, float* __restrict__ out) {
    int e = meta[32 + blockIdx.y];
    if (e < 0) return;
    int htile = blockIdx.x;                 // 0..31 (H/64)
    int tid = threadIdx.x;

    __shared__ unsigned short hs[2][PM][LDB];   // 72 KB
    __shared__ unsigned short wsm[2][64][LDB];  // 18 KB
    __shared__ int prow[PM];

    if (tid < PM) prow[tid] = meta[LIST_OFF + blockIdx.y * PM + tid];
    __syncthreads();

    const int lane = tid & 63;
    const int wid  = tid >> 6;              // 0..15
    const int l15  = lane & 15;
    const int kq   = (lane >> 4) * 8;
    const int hbk  = htile >> 1;            // h-block (128) for scales

    float4v zero = {0.f, 0.f, 0.f, 0.f};
    float4v acc[4];
#pragma unroll
    for (int t = 0; t < 4; ++t) acc[t] = zero;

    const int rx = tid >> 2, cx = tid & 3;   // h: 4 thr/row x 16 bf16
    const int rww = tid >> 4, cw = tid & 15; // w2: 16 thr/row x 4 f32
    int pr = prow[rx]; if (pr < 0) pr = 0;
    const unsigned short* hrow = hbuf + (size_t)pr * I_DIM + cx * 16;
    const float* wrow = w2g + ((size_t)e * H_DIM + htile * 64 + rww) * I_DIM + cw * 4;
    const float* s2p = s2 + ((size_t)e * (H_DIM/128) + hbk) * (I_DIM/128);

    uint4  ph[2];
    float4 pw;
    ph[0] = *(const uint4*)(hrow);
    ph[1] = *(const uint4*)(hrow + 8);
    pw = *(const float4*)(wrow);
    {   // prologue: write step 0 into buf 0
        float sc = s2p[0];
        *(uint4*)&hs[0][rx][cx * 16]     = ph[0];
        *(uint4*)&hs[0][rx][cx * 16 + 8] = ph[1];
        *(uint2*)&wsm[0][rww][cw * 4] = make_uint2(cvt2(pw.x * sc, pw.y * sc),
                                                   cvt2(pw.z * sc, pw.w * sc));
    }
    __syncthreads();

    const int NT2 = I_DIM / BK2;            // 16 steps
    int cur = 0;
    for (int t = 0; t < NT2; ++t) {
        if (t + 1 < NT2) {                  // issue next-step loads FIRST
            const int i0 = (t + 1) * BK2;
            ph[0] = *(const uint4*)(hrow + i0);
            ph[1] = *(const uint4*)(hrow + i0 + 8);
            pw = *(const float4*)(wrow + i0);
        }
        __builtin_amdgcn_sched_barrier(0);  // pin loads above the MFMA phase
#pragma unroll
        for (int ks = 0; ks < BK2 / 32; ++ks) {
            int koff = ks * 32 + kq;
            short8v af = *(const short8v*)&hs[cur][wid * 16 + l15][koff];
#pragma unroll
            for (int nt = 0; nt < 4; ++nt) {
                short8v bfv = *(const short8v*)&wsm[cur][nt * 16 + l15][koff];
                acc[nt] = __builtin_amdgcn_mfma_f32_16x16x32_bf16(af, bfv, acc[nt], 0, 0, 0);
            }
        }
        if (t + 1 < NT2) {                  // write buf[cur^1] (auto vmcnt here)
            float sc = s2p[(t + 1) >> 1];
            *(uint4*)&hs[cur ^ 1][rx][cx * 16]     = ph[0];
            *(uint4*)&hs[cur ^ 1][rx][cx * 16 + 8] = ph[1];
            *(uint2*)&wsm[cur ^ 1][rww][cw * 4] = make_uint2(cvt2(pw.x * sc, pw.y * sc),
                                                             cvt2(pw.z * sc, pw.w * sc));
        }
        __syncthreads();
        cur ^= 1;
    }

    int rowb = wid * 16 + (lane >> 4) * 4;
    int colb = htile * 64 + l15;
#pragma unroll
    for (int nt = 0; nt < 4; ++nt) {
#pragma unroll
        for (int rg = 0; rg < 4; ++rg) {
            int p = prow[rowb + rg];
            if (p < 0) continue;
            out[(size_t)p * H_DIM + colb + nt * 16] = acc[nt][rg] * rw[p];
        }
    }
}

extern "C" void kernel_launch(void* const* d_in, const int* in_sizes, int n_in,
                              void* d_out, int out_size, void* d_ws, size_t ws_size,
                              hipStream_t stream) {
    const float* x  = (const float*)d_in[0];
    const float* w0 = (const float*)d_in[1];
    const float* w1 = (const float*)d_in[2];
    const float* w2 = (const float*)d_in[3];
    const float* s0 = (const float*)d_in[4];
    const float* s1 = (const float*)d_in[5];
    const float* s2 = (const float*)d_in[6];
    const int* sel  = (const int*)d_in[7];
    const float* rw = (const float*)d_in[8];
    float* out = (float*)d_out;
    int* meta = (int*)d_ws;
    unsigned short* hbuf = (unsigned short*)((float*)d_ws + HWS_OFF);  // 2048*1024 bf16 = 4 MB

    route_kernel<<<1, 1024, 0, stream>>>(sel, meta);
    gemm01_kernel<<<dim3(I_DIM / 64, MAXCH), 1024, 0, stream>>>(x, w0, w1, s0, s1, meta, hbuf);
    gemm2_kernel<<<dim3(H_DIM / 64, MAXCH), 1024, 0, stream>>>(hbuf, w2, s2, rw, meta, out);
}